// Round 5
// baseline (235.633 us; speedup 1.0000x reference)
//
#include <hip/hip_runtime.h>
#include <math.h>

#define IN_F   256
#define OUT_F  128
#define HEADS  4
#define HD     (HEADS * OUT_F)   // 512
#define NEG    0.2f
#define CAP    64                // per-node in-edge capacity (mean deg 16; P(deg>64) ~ 1e-18)

typedef __attribute__((ext_vector_type(8))) short short8;   // 8 bf16 = 4 VGPRs
typedef __attribute__((ext_vector_type(4))) float f32x4;

typedef __attribute__((address_space(1))) const void* gp_t;
typedef __attribute__((address_space(3))) void* lp_t;

static __device__ __forceinline__ ushort f2bf(float f) {
    union { float f; unsigned u; } v; v.f = f;
    unsigned r = (v.u + 0x7FFFu + ((v.u >> 16) & 1u)) >> 16;   // RNE
    return (ushort)r;
}
static __device__ __forceinline__ float bflo(unsigned u) {
    union { unsigned u; float f; } v; v.u = u << 16; return v.f;
}
static __device__ __forceinline__ float bfhi(unsigned u) {
    union { unsigned u; float f; } v; v.u = u & 0xFFFF0000u; return v.f;
}

// ---------------- WT bf16 [512][256] + va = W @ att  (fp32 [4][256] x2) ----------------
__global__ __launch_bounds__(256) void cvt_wt(const float* __restrict__ W,
                                              ushort* __restrict__ WT) {
    int idx = blockIdx.x * blockDim.x + threadIdx.x;   // 512*256
    int n = idx >> 8, k = idx & 255;
    WT[idx] = f2bf(W[k * HD + n]);
}
__global__ __launch_bounds__(256) void calc_va(const float* __restrict__ W,
                                               const float* __restrict__ att_src,
                                               const float* __restrict__ att_dst,
                                               float* __restrict__ va_s,
                                               float* __restrict__ va_d) {
    int idx = blockIdx.x * blockDim.x + threadIdx.x;   // 4*256
    int h = idx >> 8, k = idx & 255;
    const float* wr = W + (size_t)k * HD + h * OUT_F;
    const float* as = att_src + h * OUT_F;
    const float* ad = att_dst + h * OUT_F;
    float ss = 0.f, sd = 0.f;
#pragma unroll 8
    for (int c = 0; c < OUT_F; ++c) {
        float w = wr[c];
        ss = fmaf(w, as[c], ss);
        sd = fmaf(w, ad[c], sd);
    }
    va_s[idx] = ss;
    va_d[idx] = sd;
}

// ------- fused: X f32 -> Xb bf16, plus a_s/a_d = x . va (wave per node) -------
__global__ __launch_bounds__(256) void fused_x(const float* __restrict__ X,
                                               const float* __restrict__ va_s,
                                               const float* __restrict__ va_d,
                                               ushort* __restrict__ Xb,
                                               float* __restrict__ a_s,
                                               float* __restrict__ a_d,
                                               int n_nodes) {
    const int lane = threadIdx.x & 63;
    const int node = blockIdx.x * 4 + (threadIdx.x >> 6);
    if (node >= n_nodes) return;
    float4 v = *(const float4*)(X + (size_t)node * IN_F + lane * 4);
    ushort4 o; o.x = f2bf(v.x); o.y = f2bf(v.y); o.z = f2bf(v.z); o.w = f2bf(v.w);
    *(ushort4*)(Xb + (size_t)node * IN_F + lane * 4) = o;

    float ps[HEADS], pd[HEADS];
#pragma unroll
    for (int hd = 0; hd < HEADS; ++hd) {
        float4 s4 = *(const float4*)(va_s + hd * IN_F + lane * 4);
        float4 d4 = *(const float4*)(va_d + hd * IN_F + lane * 4);
        ps[hd] = v.x * s4.x + v.y * s4.y + v.z * s4.z + v.w * s4.w;
        pd[hd] = v.x * d4.x + v.y * d4.y + v.z * d4.z + v.w * d4.w;
    }
#pragma unroll
    for (int off = 32; off > 0; off >>= 1) {
#pragma unroll
        for (int hd = 0; hd < HEADS; ++hd) {
            ps[hd] += __shfl_xor(ps[hd], off, 64);
            pd[hd] += __shfl_xor(pd[hd], off, 64);
        }
    }
    if (lane == 0) {
        float4 s4 = make_float4(ps[0], ps[1], ps[2], ps[3]);
        float4 d4 = make_float4(pd[0], pd[1], pd[2], pd[3]);
        *(float4*)(a_s + node * 4) = s4;
        *(float4*)(a_d + node * 4) = d4;
    }
}

// ---------------- Hb(bf16) = Xb @ WT^T via bf16 MFMA, global_load_lds staging ----------------
#define GBM 128
#define GBN 128
#define GBK 32

__global__ __launch_bounds__(256) void gemm_mfma(const ushort* __restrict__ Xb,
                                                 const ushort* __restrict__ WT,
                                                 ushort* __restrict__ Hb,
                                                 int n_nodes) {
    __shared__ ushort As[GBM][GBK];
    __shared__ ushort Bs[GBN][GBK];
    const int tid = threadIdx.x;
    const int m0 = blockIdx.y * GBM;
    const int n0 = blockIdx.x * GBN;
    const int wave = tid >> 6, lane = tid & 63;
    const int wm = (wave & 1) * 64, wn = (wave >> 1) * 64;
    const int l15 = lane & 15, quad = lane >> 4;

    const int rr = lane >> 2;
    const int cg = (lane & 3) ^ ((lane >> 3) & 3);
    const int rA = wave * 16 + rr;
    const ushort* gA0 = Xb + (size_t)(m0 + rA) * IN_F + cg * 8;
    const ushort* gA1 = Xb + (size_t)(m0 + 64 + rA) * IN_F + cg * 8;
    const ushort* gB0 = WT + (size_t)(n0 + rA) * IN_F + cg * 8;
    const ushort* gB1 = WT + (size_t)(n0 + 64 + rA) * IN_F + cg * 8;
    ushort* lA0 = &As[wave * 16][0];
    ushort* lA1 = &As[64 + wave * 16][0];
    ushort* lB0 = &Bs[wave * 16][0];
    ushort* lB1 = &Bs[64 + wave * 16][0];

    f32x4 acc[4][4];
#pragma unroll
    for (int i = 0; i < 4; ++i)
#pragma unroll
        for (int j = 0; j < 4; ++j) acc[i][j] = (f32x4){0.f, 0.f, 0.f, 0.f};

    const int ks = (quad ^ ((l15 >> 1) & 3)) * 8;

    for (int k0 = 0; k0 < IN_F; k0 += GBK) {
        __syncthreads();
        __builtin_amdgcn_global_load_lds((gp_t)(gA0 + k0), (lp_t)lA0, 16, 0, 0);
        __builtin_amdgcn_global_load_lds((gp_t)(gA1 + k0), (lp_t)lA1, 16, 0, 0);
        __builtin_amdgcn_global_load_lds((gp_t)(gB0 + k0), (lp_t)lB0, 16, 0, 0);
        __builtin_amdgcn_global_load_lds((gp_t)(gB1 + k0), (lp_t)lB1, 16, 0, 0);
        __syncthreads();

        short8 af[4], bf_[4];
#pragma unroll
        for (int f = 0; f < 4; ++f) {
            af[f]  = *(const short8*)&As[wm + f * 16 + l15][ks];
            bf_[f] = *(const short8*)&Bs[wn + f * 16 + l15][ks];
        }
#pragma unroll
        for (int fm = 0; fm < 4; ++fm)
#pragma unroll
            for (int fn = 0; fn < 4; ++fn)
                acc[fm][fn] = __builtin_amdgcn_mfma_f32_16x16x32_bf16(
                    af[fm], bf_[fn], acc[fm][fn], 0, 0, 0);
    }

#pragma unroll
    for (int fm = 0; fm < 4; ++fm) {
        int gmb = m0 + wm + fm * 16 + quad * 4;
#pragma unroll
        for (int reg = 0; reg < 4; ++reg) {
            int gm = gmb + reg;
            if (gm < n_nodes) {
#pragma unroll
                for (int fn = 0; fn < 4; ++fn)
                    Hb[(size_t)gm * HD + n0 + wn + fn * 16 + l15] =
                        f2bf(acc[fm][fn][reg]);
            }
        }
    }
}

// --------- transpose Hb [n][head][pairlane] -> Hc [n][pairlane][head] (uint = bf16 pair) ---------
__global__ __launch_bounds__(256) void transpose_h(const unsigned* __restrict__ Hbu,
                                                   uint4* __restrict__ Hc, int n_nodes) {
    const int lane = threadIdx.x & 63;
    const int n = blockIdx.x * 4 + (threadIdx.x >> 6);
    if (n >= n_nodes) return;
    const unsigned* p = Hbu + (size_t)n * 256;
    uint4 v;
    v.x = p[lane];
    v.y = p[64 + lane];
    v.z = p[128 + lane];
    v.w = p[192 + lane];
    Hc[(size_t)n * 64 + lane] = v;   // 16B/lane contiguous
}

// --------- bucket edges by dst: table[d][r] = src ---------
__global__ __launch_bounds__(256) void build_table(const int* __restrict__ src,
                                                   const int* __restrict__ dst,
                                                   int* __restrict__ cursor,
                                                   int* __restrict__ table,
                                                   int n_edges) {
    int e = blockIdx.x * blockDim.x + threadIdx.x;
    if (e >= n_edges) return;
    int d = dst[e];
    int r = atomicAdd(&cursor[d], 1);
    if (r < CAP) table[(size_t)d * CAP + r] = src[e];
}

// --------- fused softmax + aggregation: wave per node ---------
// lane-per-edge softmax; weights staged in wave-local LDS (uniform float4 broadcast reads);
// gathers are one dwordx4 per edge per lane from head-interleaved Hc.
__global__ __launch_bounds__(256) void gat_agg(const uint4* __restrict__ Hc,
                                               const float* __restrict__ a_s,
                                               const float* __restrict__ a_d,
                                               const int* __restrict__ cursor,
                                               const int* __restrict__ table,
                                               const float* __restrict__ bias,
                                               float* __restrict__ out,
                                               int n_nodes) {
    __shared__ float wsh[4][CAP][4];
    const int wv = threadIdx.x >> 6;
    const int lane = threadIdx.x & 63;
    const int n = blockIdx.x * 4 + wv;
    const bool valid = n < n_nodes;

    int deg = 0;
    const int* row = table;
    float es[4], rdv[4];
    if (valid) {
        deg = cursor[n]; if (deg > CAP) deg = CAP;
        row = table + (size_t)n * CAP;

        const float4 ad4 = *(const float4*)(a_d + n * 4);
        const float4 as4 = *(const float4*)(a_s + n * 4);
        const float ad[4] = {ad4.x, ad4.y, ad4.z, ad4.w};
        float aself[4];
        {
            const float asn[4] = {as4.x, as4.y, as4.z, as4.w};
#pragma unroll
            for (int hd = 0; hd < 4; ++hd) {
                float al = asn[hd] + ad[hd];
                aself[hd] = al > 0.f ? al : NEG * al;
            }
        }
        const bool act = lane < deg;
        float al[4];
        {
            int s = act ? row[lane] : 0;
            float4 av = *(const float4*)(a_s + s * 4);
            const float as_[4] = {av.x, av.y, av.z, av.w};
#pragma unroll
            for (int hd = 0; hd < 4; ++hd) {
                float a = as_[hd] + ad[hd];
                a = a > 0.f ? a : NEG * a;
                al[hd] = act ? a : -1e30f;
            }
        }
        float m[4];
#pragma unroll
        for (int hd = 0; hd < 4; ++hd) m[hd] = al[hd];
#pragma unroll
        for (int off = 32; off > 0; off >>= 1)
#pragma unroll
            for (int hd = 0; hd < 4; ++hd)
                m[hd] = fmaxf(m[hd], __shfl_xor(m[hd], off, 64));
#pragma unroll
        for (int hd = 0; hd < 4; ++hd) m[hd] = fmaxf(m[hd], aself[hd]);

        float w[4], den[4];
#pragma unroll
        for (int hd = 0; hd < 4; ++hd) {
            w[hd] = act ? __expf(al[hd] - m[hd]) : 0.f;
            den[hd] = w[hd];
        }
#pragma unroll
        for (int off = 32; off > 0; off >>= 1)
#pragma unroll
            for (int hd = 0; hd < 4; ++hd)
                den[hd] += __shfl_xor(den[hd], off, 64);
#pragma unroll
        for (int hd = 0; hd < 4; ++hd) {
            es[hd] = __expf(aself[hd] - m[hd]);
            rdv[hd] = 1.f / (den[hd] + es[hd]);
        }
        *(float4*)&wsh[wv][lane][0] = make_float4(w[0], w[1], w[2], w[3]);
    }
    __syncthreads();
    if (!valid) return;

    // ---- aggregation: 1 dwordx4 gather per edge per lane ----
    float acc0[4], acc1[4];
    {
        uint4 u = Hc[(size_t)n * 64 + lane];
        acc0[0] = es[0] * bflo(u.x); acc1[0] = es[0] * bfhi(u.x);
        acc0[1] = es[1] * bflo(u.y); acc1[1] = es[1] * bfhi(u.y);
        acc0[2] = es[2] * bflo(u.z); acc1[2] = es[2] * bfhi(u.z);
        acc0[3] = es[3] * bflo(u.w); acc1[3] = es[3] * bfhi(u.w);
    }
    int e = 0;
    for (; e + 8 <= deg; e += 8) {
        int4 ra = *(const int4*)(row + e);
        int4 rb = *(const int4*)(row + e + 4);
        uint4 u[8];
        u[0] = Hc[(size_t)ra.x * 64 + lane];
        u[1] = Hc[(size_t)ra.y * 64 + lane];
        u[2] = Hc[(size_t)ra.z * 64 + lane];
        u[3] = Hc[(size_t)ra.w * 64 + lane];
        u[4] = Hc[(size_t)rb.x * 64 + lane];
        u[5] = Hc[(size_t)rb.y * 64 + lane];
        u[6] = Hc[(size_t)rb.z * 64 + lane];
        u[7] = Hc[(size_t)rb.w * 64 + lane];
#pragma unroll
        for (int j = 0; j < 8; ++j) {
            float4 w4 = *(const float4*)&wsh[wv][e + j][0];
            acc0[0] = fmaf(w4.x, bflo(u[j].x), acc0[0]);
            acc1[0] = fmaf(w4.x, bfhi(u[j].x), acc1[0]);
            acc0[1] = fmaf(w4.y, bflo(u[j].y), acc0[1]);
            acc1[1] = fmaf(w4.y, bfhi(u[j].y), acc1[1]);
            acc0[2] = fmaf(w4.z, bflo(u[j].z), acc0[2]);
            acc1[2] = fmaf(w4.z, bfhi(u[j].z), acc1[2]);
            acc0[3] = fmaf(w4.w, bflo(u[j].w), acc0[3]);
            acc1[3] = fmaf(w4.w, bfhi(u[j].w), acc1[3]);
        }
    }
    for (; e < deg; ++e) {
        int s = row[e];
        uint4 u = Hc[(size_t)s * 64 + lane];
        float4 w4 = *(const float4*)&wsh[wv][e][0];
        acc0[0] = fmaf(w4.x, bflo(u.x), acc0[0]);
        acc1[0] = fmaf(w4.x, bfhi(u.x), acc1[0]);
        acc0[1] = fmaf(w4.y, bflo(u.y), acc0[1]);
        acc1[1] = fmaf(w4.y, bfhi(u.y), acc1[1]);
        acc0[2] = fmaf(w4.z, bflo(u.z), acc0[2]);
        acc1[2] = fmaf(w4.z, bfhi(u.z), acc1[2]);
        acc0[3] = fmaf(w4.w, bflo(u.w), acc0[3]);
        acc1[3] = fmaf(w4.w, bfhi(u.w), acc1[3]);
    }
    float o0 = 0.f, o1 = 0.f;
#pragma unroll
    for (int hd = 0; hd < 4; ++hd) {
        o0 = fmaf(acc0[hd], rdv[hd], o0);
        o1 = fmaf(acc1[hd], rdv[hd], o1);
    }
    float2 b = *(const float2*)(bias + 2 * lane);
    o0 = 0.25f * o0 + b.x;
    o1 = 0.25f * o1 + b.y;
    float2 ov = make_float2(tanhf(o0), tanhf(o1));
    *(float2*)(out + (size_t)n * OUT_F + 2 * lane) = ov;
}

extern "C" void kernel_launch(void* const* d_in, const int* in_sizes, int n_in,
                              void* d_out, int out_size, void* d_ws, size_t ws_size,
                              hipStream_t stream) {
    const float* x       = (const float*)d_in[0];
    const int*   ei      = (const int*)d_in[1];
    const float* W       = (const float*)d_in[2];
    const float* att_src = (const float*)d_in[3];
    const float* att_dst = (const float*)d_in[4];
    const float* bias    = (const float*)d_in[5];
    float* out = (float*)d_out;

    const int n_nodes = in_sizes[0] / IN_F;     // 30000
    const int n_edges = in_sizes[1] / 2;        // 480000
    const int* src = ei;
    const int* dst = ei + n_edges;

    char* ws = (char*)d_ws;
    size_t off = 0;
    auto alloc = [&](size_t bytes) -> void* {
        void* p = ws + off;
        off = (off + bytes + 255) & ~(size_t)255;
        return p;
    };
    ushort* Xb     = (ushort*)alloc((size_t)n_nodes * IN_F * sizeof(ushort));   // 15.4 MB
    ushort* Hb     = (ushort*)alloc((size_t)n_nodes * HD * sizeof(ushort));     // 30.7 MB
    uint4*  Hc     = (uint4*)alloc((size_t)n_nodes * 64 * sizeof(uint4));       // 30.7 MB
    ushort* WT     = (ushort*)alloc((size_t)HD * IN_F * sizeof(ushort));        // 0.26 MB
    float*  va_s   = (float*)alloc((size_t)HEADS * IN_F * sizeof(float));
    float*  va_d   = (float*)alloc((size_t)HEADS * IN_F * sizeof(float));
    float*  a_s    = (float*)alloc((size_t)n_nodes * HEADS * sizeof(float));
    float*  a_d    = (float*)alloc((size_t)n_nodes * HEADS * sizeof(float));
    int*    cursor = (int*)alloc((size_t)n_nodes * sizeof(int));
    int*    table  = (int*)alloc((size_t)n_nodes * CAP * sizeof(int));          // 7.7 MB
    (void)ws_size; (void)n_in; (void)out_size;

    hipMemsetAsync(cursor, 0, (size_t)n_nodes * sizeof(int), stream);

    cvt_wt<<<(HD * IN_F) / 256, 256, 0, stream>>>(W, WT);
    calc_va<<<(HEADS * IN_F) / 256, 256, 0, stream>>>(W, att_src, att_dst, va_s, va_d);
    fused_x<<<(n_nodes + 3) / 4, 256, 0, stream>>>(x, va_s, va_d, Xb, a_s, a_d, n_nodes);
    build_table<<<(n_edges + 255) / 256, 256, 0, stream>>>(src, dst, cursor, table, n_edges);

    dim3 ggrid(HD / GBN, (n_nodes + GBM - 1) / GBM);   // 4 x 235
    gemm_mfma<<<ggrid, 256, 0, stream>>>(Xb, WT, Hb, n_nodes);
    transpose_h<<<(n_nodes + 3) / 4, 256, 0, stream>>>((const unsigned*)Hb, Hc, n_nodes);

    gat_agg<<<(n_nodes + 3) / 4, 256, 0, stream>>>(Hc, a_s, a_d, cursor, table,
                                                   bias, out, n_nodes);
}